// Round 9
// baseline (204.057 us; speedup 1.0000x reference)
//
#include <hip/hip_runtime.h>
#include <math.h>

#define NB 16
#define NL 1024
#define NH 8
#define NE 64
#define NWIN 1024
#define NG 64

#define SCH 64      // s-chunk per block in k_attn_out
#define SROW 72     // sb row stride in shorts (72*2=144 B, 16B-aligned)
#define NCH 16      // s-chunks per (b,h)
#define PADW 1032   // wb row stride in shorts (2064 B: 16B-aligned, bank-spread)

typedef __attribute__((ext_vector_type(8))) short short8;
typedef __attribute__((ext_vector_type(4))) short short4v;
typedef __attribute__((ext_vector_type(4))) float floatx4;

__device__ __forceinline__ short f2bf(float x) {
    unsigned u = __float_as_uint(x);
    u += 0x7fffu + ((u >> 16) & 1u);   // round-to-nearest-even
    return (short)(u >> 16);
}
__device__ __forceinline__ float dot4(float4 a, float4 b) {
    return fmaf(a.x, b.x, fmaf(a.y, b.y, fmaf(a.z, b.z, a.w * b.w)));
}

// Fused tanh-MLP + qp/qn, v5: MLP as MFMA GEMM [16384x1024]x[1024x8].
// The K-reduction happens inside the matrix pipe — the 6-deep shuffle merge
// trees (the dependent chain that pinned 4 prior variants at ~41 µs) are
// gone. A-frags (x) load straight from global: lane(c,q) reads 8 contiguous
// floats = A[m=c][k=q*8+j]; B = w staged bf16 in LDS. Block = 4 waves x 16
// rows = 64 rows, grid 256 (1 block/CU), explicit double-buffered k-loop.
__global__ __launch_bounds__(256) void k_sel_q(
    const float* __restrict__ x, const float* __restrict__ mlp_w,
    const float* __restrict__ mlp_b, const float* __restrict__ q,
    float* __restrict__ qp, float* __restrict__ qn)
{
    __shared__ short wb[8][PADW];       // 16.5 KB  w in bf16
    __shared__ float t_lds[512];
    __shared__ float redp[4][64], redn[4][64];

    int tid = threadIdx.x, blk = blockIdx.x;
    int half = blk & 1, h = (blk >> 1) & 7, b = blk >> 4;
    int bh = b * 8 + h;
    int w = tid >> 6, lane = tid & 63;
    int c = lane & 15, qd = lane >> 4;

    // ---- stage w -> bf16 LDS ----
    {
        int row = tid >> 5;             // 0..7
        int seg = tid & 31;             // k-range seg*32 .. +32
        const float4* src = (const float4*)(mlp_w + (size_t)row * NWIN + seg * 32);
        #pragma unroll
        for (int i = 0; i < 8; ++i) {
            float4 v = src[i];
            short4v s4 = {f2bf(v.x), f2bf(v.y), f2bf(v.z), f2bf(v.w)};
            *(short4v*)&wb[row][seg * 32 + i * 4] = s4;
        }
    }
    __syncthreads();

    // ---- MFMA MLP: wave w owns rows rw..rw+15 (l8 = half*64 + w*16 + m) ----
    int rw = b * 1024 + h * 128 + half * 64 + w * 16;
    const float* xrow = x + (size_t)(rw + c) * NWIN + qd * 8;
    floatx4 acc = {0.f, 0.f, 0.f, 0.f};
    float4 a0a = *(const float4*)(xrow);
    float4 a0b = *(const float4*)(xrow + 4);
    #pragma unroll 8
    for (int ks = 0; ks < 32; ++ks) {
        float4 a1a, a1b;
        if (ks < 31) {
            a1a = *(const float4*)(xrow + (ks + 1) * 32);
            a1b = *(const float4*)(xrow + (ks + 1) * 32 + 4);
        }
        short8 av;
        av[0] = f2bf(a0a.x); av[1] = f2bf(a0a.y);
        av[2] = f2bf(a0a.z); av[3] = f2bf(a0a.w);
        av[4] = f2bf(a0b.x); av[5] = f2bf(a0b.y);
        av[6] = f2bf(a0b.z); av[7] = f2bf(a0b.w);
        short8 bv = {0,0,0,0,0,0,0,0};
        if (c < 8) bv = *(const short8*)&wb[c][ks * 32 + qd * 8];
        acc = __builtin_amdgcn_mfma_f32_16x16x32_bf16(av, bv, acc, 0, 0, 0);
        a0a = a1a; a0b = a1b;
    }
    // D[row=qd*4+r][col=c]; col c<8 are the 8 MLP outputs (c>=8 got B=0)
    if (c < 8) {
        float bias = mlp_b[c];
        #pragma unroll
        for (int r = 0; r < 4; ++r) {
            int l8 = w * 16 + qd * 4 + r;
            t_lds[l8 * 8 + c] = tanhf(acc[r] + bias);
        }
    }
    __syncthreads();

    // ---- phase 2: qp/qn over this block's 512 l-values ----
    int lo = lane >> 4, e4 = lane & 15;
    float4 accp = make_float4(0,0,0,0), accn = make_float4(0,0,0,0);
    #pragma unroll 4
    for (int i = 0; i < 32; ++i) {
        int l_loc = w * 128 + i * 4 + lo;
        float tv = t_lds[l_loc];
        int l = half * 512 + l_loc;
        float4 qv = *(const float4*)(q + (((size_t)(b * NL + l)) * NH + h) * NE + e4 * 4);
        float tp = fmaxf(tv, 0.f), tn = fminf(tv, 0.f);
        accp.x = fmaf(tp, qv.x, accp.x); accp.y = fmaf(tp, qv.y, accp.y);
        accp.z = fmaf(tp, qv.z, accp.z); accp.w = fmaf(tp, qv.w, accp.w);
        accn.x = fmaf(tn, qv.x, accn.x); accn.y = fmaf(tn, qv.y, accn.y);
        accn.z = fmaf(tn, qv.z, accn.z); accn.w = fmaf(tn, qv.w, accn.w);
    }
    #pragma unroll
    for (int off = 16; off <= 32; off <<= 1) {
        accp.x += __shfl_xor(accp.x, off, 64); accp.y += __shfl_xor(accp.y, off, 64);
        accp.z += __shfl_xor(accp.z, off, 64); accp.w += __shfl_xor(accp.w, off, 64);
        accn.x += __shfl_xor(accn.x, off, 64); accn.y += __shfl_xor(accn.y, off, 64);
        accn.z += __shfl_xor(accn.z, off, 64); accn.w += __shfl_xor(accn.w, off, 64);
    }
    if (lo == 0) {
        *(float4*)&redp[w][e4 * 4] = accp;
        *(float4*)&redn[w][e4 * 4] = accn;
    }
    __syncthreads();
    if (tid < 64) {
        atomicAdd(&qp[bh * NE + tid], redp[0][tid] + redp[1][tid] + redp[2][tid] + redp[3][tid]);
    } else if (tid < 128) {
        int e = tid - 64;
        atomicAdd(&qn[bh * NE + e], redn[0][e] + redn[1][e] + redn[2][e] + redn[3][e]);
    }
}

// Attention v8 (unchanged from round 8): per (b, h, s-chunk of 64),
// h in low blockIdx bits, k/v prefetched to registers, softmax 4-way split,
// PV via MFMA, partials to ws.
__global__ __launch_bounds__(256) void k_attn_out(
    const float* __restrict__ keys, const float* __restrict__ values,
    const float* __restrict__ sel_W,
    const float* __restrict__ qp, const float* __restrict__ qn,
    float* __restrict__ partial)
{
    __shared__ short sb[NG][SROW];          // 9.2 KB  series bf16 [g][s]
    __shared__ float ap_l[SCH], an_l[SCH];
    __shared__ float2 wpn[NG];
    __shared__ float mx4[4][SCH], dn4[4][SCH];

    int tid = threadIdx.x, blk = blockIdx.x;
    int h = blk & 7;
    int chunk = (blk >> 3) & (NCH - 1);
    int b = blk >> 7;
    int bh = b * 8 + h;
    int w = tid >> 6, lane = tid & 63;
    int c = lane & 15, sq = lane >> 4;
    const float scale = 0.125f;             // 1/sqrt(64)
    int s0 = chunk * SCH;

    // ---- prefetch: v (16 scalars) + k (4 float4) ----
    float vt[16];
    const float* vbase = values + (((size_t)(b * NL + s0)) * NH + h) * NE + 16 * w + c;
    #pragma unroll
    for (int ks = 0; ks < 2; ++ks)
        #pragma unroll
        for (int j = 0; j < 8; ++j)
            vt[ks * 8 + j] = vbase[(size_t)(ks * 32 + sq * 8 + j) * (NH * NE)];
    float4 k4[4];
    #pragma unroll
    for (int p = 0; p < 4; ++p) {
        int sl = w * 16 + p * 4 + sq;
        k4[p] = *(const float4*)(keys + (((size_t)(b * NL + s0 + sl)) * NH + h) * NE + c * 4);
    }
    __builtin_amdgcn_sched_barrier(0);

    if (tid < NG) {
        float W = sel_W[h * NG + tid];
        wpn[tid] = make_float2(fmaxf(W, 0.f) * scale, fminf(W, 0.f) * scale);
    }
    const float4 qp4 = *(const float4*)(qp + bh * NE + c * 4);
    const float4 qn4 = *(const float4*)(qn + bh * NE + c * 4);

    // ---- phase A: ap/an (wave owns 16 s) ----
    #pragma unroll
    for (int p = 0; p < 4; ++p) {
        int sl = w * 16 + p * 4 + sq;
        float pp = dot4(k4[p], qp4);
        float pn = dot4(k4[p], qn4);
        #pragma unroll
        for (int m_ = 1; m_ <= 8; m_ <<= 1) {
            pp += __shfl_xor(pp, m_, 64);
            pn += __shfl_xor(pn, m_, 64);
        }
        if (c == 0) { ap_l[sl] = pp; an_l[sl] = pn; }
    }
    __syncthreads();

    // ---- phase B: softmax over g, g-range split 4-way ----
    {
        int s_ = tid & 63, q4i = tid >> 6, g0 = q4i * 16;
        float ap = ap_l[s_], an = an_l[s_];
        float m = -1e30f;
        #pragma unroll
        for (int g = 0; g < 16; ++g) {
            float2 wv = wpn[g0 + g];
            m = fmaxf(m, fmaf(wv.x, ap, wv.y * an));
        }
        mx4[q4i][s_] = m;
        __syncthreads();
        m = fmaxf(fmaxf(mx4[0][s_], mx4[1][s_]), fmaxf(mx4[2][s_], mx4[3][s_]));
        float d = 0.f;
        #pragma unroll
        for (int g = 0; g < 16; ++g) {
            float2 wv = wpn[g0 + g];
            d += __expf(fmaf(wv.x, ap, wv.y * an) - m);
        }
        dn4[q4i][s_] = d;
        __syncthreads();
        float inv = 1.0f / (dn4[0][s_] + dn4[1][s_] + dn4[2][s_] + dn4[3][s_]);
        #pragma unroll
        for (int g = 0; g < 16; ++g) {
            float2 wv = wpn[g0 + g];
            sb[g0 + g][s_] = f2bf(__expf(fmaf(wv.x, ap, wv.y * an) - m) * inv);
        }
    }
    __syncthreads();

    // ---- phase C: pack v, MFMA; wave owns e-tile [16w, 16w+16) ----
    floatx4 acc[4] = {{0.f,0.f,0.f,0.f},{0.f,0.f,0.f,0.f},
                      {0.f,0.f,0.f,0.f},{0.f,0.f,0.f,0.f}};
    #pragma unroll
    for (int ks = 0; ks < 2; ++ks) {
        short8 av;
        #pragma unroll
        for (int j = 0; j < 8; ++j) av[j] = f2bf(vt[ks * 8 + j]);
        #pragma unroll
        for (int n = 0; n < 4; ++n) {
            short8 bv = *(const short8*)&sb[16 * n + c][ks * 32 + sq * 8];
            acc[n] = __builtin_amdgcn_mfma_f32_16x16x32_bf16(av, bv, acc[n], 0, 0, 0);
        }
    }

    // epilogue: partial[chunk][out_flat], out_flat = ((b*64+e)*8+h)*64+g
    float* pch = partial + (size_t)chunk * (NB * NE * NH * NG);
    #pragma unroll
    for (int n = 0; n < 4; ++n) {
        #pragma unroll
        for (int r = 0; r < 4; ++r) {
            int e = 16 * w + sq * 4 + r;
            int g = 16 * n + c;
            pch[((size_t)(b * NE + e) * NH + h) * NG + g] = acc[n][r];
        }
    }
}

// Sum the 16 chunk-partials -> out. Fully coalesced float4.
__global__ __launch_bounds__(256) void k_reduce(
    const float* __restrict__ partial, float* __restrict__ out)
{
    int i = blockIdx.x * 256 + threadIdx.x;     // float4 index, 131072 total
    const float4* p = (const float4*)partial;
    float4 s = p[i];
    #pragma unroll
    for (int ch = 1; ch < NCH; ++ch) {
        float4 t = p[(size_t)ch * 131072 + i];
        s.x += t.x; s.y += t.y; s.z += t.z; s.w += t.w;
    }
    ((float4*)out)[i] = s;
}

extern "C" void kernel_launch(void* const* d_in, const int* in_sizes, int n_in,
                              void* d_out, int out_size, void* d_ws, size_t ws_size,
                              hipStream_t stream) {
    (void)in_sizes; (void)n_in; (void)ws_size; (void)out_size;
    const float* queries = (const float*)d_in[0];
    const float* keys    = (const float*)d_in[1];
    const float* values  = (const float*)d_in[2];
    const float* x       = (const float*)d_in[3];
    const float* mlp_w   = (const float*)d_in[4];
    const float* mlp_b   = (const float*)d_in[5];
    const float* sel_W   = (const float*)d_in[6];
    float* out = (float*)d_out;

    // ws layout (floats): partial[16 * 524288] | qp[8192] | qn[8192]
    float* partial = (float*)d_ws;
    float* qp_ws = partial + (size_t)NCH * (NB * NE * NH * NG);
    float* qn_ws = qp_ws + NB * NH * NE;

    hipMemsetAsync(qp_ws, 0, (size_t)2 * NB * NH * NE * sizeof(float), stream);

    k_sel_q<<<dim3(NB * NH * 2), dim3(256), 0, stream>>>(x, mlp_w, mlp_b,
                                                          queries, qp_ws, qn_ws);
    k_attn_out<<<dim3(NB * NH * NCH), dim3(256), 0, stream>>>(keys, values, sel_W,
                                                              qp_ws, qn_ws, partial);
    k_reduce<<<dim3(512), dim3(256), 0, stream>>>(partial, out);
}